// Round 2
// baseline (14136.856 us; speedup 1.0000x reference)
//
#include <hip/hip_runtime.h>
#include <hip/hip_fp16.h>

typedef _Float16 h16;
typedef _Float16 half8 __attribute__((ext_vector_type(8)));
typedef _Float16 half4v __attribute__((ext_vector_type(4)));
typedef float f32x4 __attribute__((ext_vector_type(4)));
typedef unsigned long long u64;

#define NS 2048
#define NH 512
#define NV 128
#define NE 256

// workspace layout (bytes)
#define WS_M2    0            // float [128][512]  : emb@Wx + bx + bh
#define WS_WHT   (256*1024)   // h16   [512][512]  : WhT[n][k] = Wh[k][n]
#define WS_WFCT  (768*1024)   // h16   [128][512]  : WfcT[v][k] = Wfc[k][v]
#define WS_EXCH  (896*1024)   // h16   [4 pair][2 clus][2 slot][2 side][16][256]
#define WS_FLAG  (1152*1024)  // int   [512] : flag at ((pair*2+ci)*2+side)*32

__device__ __forceinline__ float tanh_fast(float v) {
  float e = __expf(2.0f * v);
  return 1.0f - __fdividef(2.0f, e + 1.0f);
}

// ---------------- prep: M2 table, transposed f16 weights, flag zeroing ----------------
__global__ void vrnn_prep(const float* __restrict__ emb, const float* __restrict__ Wx,
                          const float* __restrict__ bx, const float* __restrict__ Wh,
                          const float* __restrict__ bh, const float* __restrict__ Wfc,
                          unsigned char* __restrict__ ws) {
  float* M2 = (float*)(ws + WS_M2);
  h16* WhT = (h16*)(ws + WS_WHT);
  h16* WfcT = (h16*)(ws + WS_WFCT);
  int* flags = (int*)(ws + WS_FLAG);
  const int bid = blockIdx.x, tid = threadIdx.x;
  if (bid < 128) {
    __shared__ float le[NE];
    le[tid] = emb[bid*NE + tid];
    __syncthreads();
    for (int hh = 0; hh < 2; ++hh) {
      int n = tid + hh*256;
      float s = bx[n] + bh[n];
      for (int e = 0; e < NE; ++e) s = fmaf(le[e], Wx[e*NH + n], s);
      M2[bid*NH + n] = s;
    }
  } else if (bid < 192) {
    const int base = (bid - 128)*4096;
    for (int i = 0; i < 16; ++i) {
      int idx = base + i*256 + tid;           // idx = k*512 + n
      WhT[(idx & 511)*NH + (idx >> 9)] = (h16)Wh[idx];
    }
  } else if (bid < 208) {
    const int base = (bid - 192)*4096;
    for (int i = 0; i < 16; ++i) {
      int idx = base + i*256 + tid;           // idx = k*128 + v
      WfcT[(idx & 127)*NH + (idx >> 7)] = (h16)Wfc[idx];
    }
  } else {
    flags[tid] = 0;
    flags[tid + 256] = 0;
  }
}

// 16-slice MFMA pass over hlds[CI][BUF] into acc[0..3], oacc (weights from AGPR)
#define COMPUTE16(CI, BUF)                                                     \
  {                                                                            \
    half8 bfr[8];                                                              \
    _Pragma("unroll")                                                          \
    for (int i = 0; i < 8; ++i)                                                \
      bfr[i] = *(const half8*)&hlds[CI][BUF][m][((i*32) + g*8) ^ swz];         \
    _Pragma("unroll")                                                          \
    for (int i = 0; i < 8; ++i) {                                              \
      _Pragma("unroll")                                                        \
      for (int nt = 0; nt < 4; ++nt)                                           \
        acc[nt] = __builtin_amdgcn_mfma_f32_16x16x32_f16(                      \
            __builtin_bit_cast(half8, whf[nt][i]), bfr[i], acc[nt], 0, 0, 0);  \
      oacc = __builtin_amdgcn_mfma_f32_16x16x32_f16(                           \
          __builtin_bit_cast(half8, wfcf[i]), bfr[i], oacc, 0, 0, 0);          \
    }                                                                          \
    _Pragma("unroll")                                                          \
    for (int i = 0; i < 8; ++i)                                                \
      bfr[i] = *(const half8*)&hlds[CI][BUF][m][(((i+8)*32) + g*8) ^ swz];     \
    _Pragma("unroll")                                                          \
    for (int i = 0; i < 8; ++i) {                                              \
      _Pragma("unroll")                                                        \
      for (int nt = 0; nt < 4; ++nt)                                           \
        acc[nt] = __builtin_amdgcn_mfma_f32_16x16x32_f16(                      \
            __builtin_bit_cast(half8, whf[nt][8+i]), bfr[i], acc[nt], 0, 0, 0);\
      oacc = __builtin_amdgcn_mfma_f32_16x16x32_f16(                           \
          __builtin_bit_cast(half8, wfcf[8+i]), bfr[i], oacc, 0, 0, 0);        \
    }                                                                          \
  }

// ---------------- RNN scan: 4 pairs x 2 CUs, 2 clusters per pair ----------------
// block b: pair = b&3 (rows 32*pair..+32, clusters X=rows+0..15, Y=rows+16..31),
// side = b>>2 (h cols side*256..+256). Wh[.,side-half] register(AGPR)-resident.
__global__ void __launch_bounds__(256, 1)
vrnn_scan(const int* __restrict__ x, const float* __restrict__ bfc,
          float* __restrict__ out, unsigned char* __restrict__ ws) {
  const float* M2 = (const float*)(ws + WS_M2);
  const h16* WhT = (const h16*)(ws + WS_WHT);
  const h16* WfcT = (const h16*)(ws + WS_WFCT);
  h16* exch = (h16*)(ws + WS_EXCH);
  int* flags = (int*)(ws + WS_FLAG);

  const int bid = blockIdx.x;
  const int pair = bid & 3;
  const int side = bid >> 2;
  const int rowX = pair * 32;
  const int rowY = rowX + 16;
  const int tid = threadIdx.x;
  const int w = tid >> 6;        // wave 0..3 (1 per SIMD)
  const int l = tid & 63;
  const int m = l & 15;          // batch row within cluster / MFMA 16-dim
  const int g = l >> 4;          // k-chunk group 0..3
  const int swz = (m & 7) << 3;  // LDS XOR swizzle (element units)
  // import-write mapping constants
  const int mm = w*4 + g;
  const int swzm = (mm & 7) << 3;
  const int pk = (1 - side)*256 + m*16;

  const int n0w = side*256 + w*64;   // this wave's Wh output columns
  const int v0w = side*64 + w*16;    // this wave's Wfc output columns

  __shared__ h16 hlds[2][2][16][NH];   // [cluster][buf][m][k], 64 KiB

  { u64* z = (u64*)&hlds[0][0][0][0];
#pragma unroll
    for (int i = 0; i < 32; ++i) z[tid + i*256] = 0ull; }   // h_{-1}=0

  // weights: f32x4-typed storage pinned to AGPRs, bit_cast to half8 at MFMA
  f32x4 whf[4][16];
  f32x4 wfcf[16];
#pragma unroll
  for (int ks = 0; ks < 16; ++ks) {
#pragma unroll
    for (int nt = 0; nt < 4; ++nt)
      whf[nt][ks] = *(const f32x4*)&WhT[(n0w + nt*16 + m)*NH + ks*32 + g*8];
    wfcf[ks] = *(const f32x4*)&WfcT[(v0w + m)*NH + ks*32 + g*8];
  }
#pragma unroll
  for (int ks = 0; ks < 16; ++ks) {
#pragma unroll
    for (int nt = 0; nt < 4; ++nt)
      asm volatile("" : "+a"(whf[nt][ks]));
    asm volatile("" : "+a"(wfcf[ks]));
  }

  const f32x4 bfcf = *(const f32x4*)&bfc[v0w + g*4];

  int* fXown = flags + ((pair*2 + 0)*2 + side)*32;
  int* fXpar = flags + ((pair*2 + 0)*2 + (1 - side))*32;
  int* fYown = flags + ((pair*2 + 1)*2 + side)*32;
  int* fYpar = flags + ((pair*2 + 1)*2 + (1 - side))*32;

  h16*       exoX = exch + (((pair*2 + 0)*2 + 0)*2 + side)*4096;        // + slot*8192
  const h16* exiX = exch + (((pair*2 + 0)*2 + 0)*2 + (1 - side))*4096;
  h16*       exoY = exch + (((pair*2 + 1)*2 + 0)*2 + side)*4096;
  const h16* exiY = exch + (((pair*2 + 1)*2 + 0)*2 + (1 - side))*4096;

  const int* xrowX = x + (rowX + m)*NS;
  const int* xrowY = x + (rowY + m)*NS;
  int tokX = xrowX[0], tokY = xrowY[0];

  u64 dX0=0, dX1=0, dX2=0, dX3=0;   // in-flight import for cluster X (partner h)
  u64 dY0=0, dY1=0, dY2=0, dY3=0;   // in-flight import for cluster Y

  __syncthreads();

  for (int t = 0; t < NS; ++t) {
    const int p = t & 1, pn = p ^ 1;
    const int tnext = (t + 1 < NS) ? (t + 1) : (NS - 1);

    // ================= PHASE X (cluster rows rowX..rowX+15) =================
    {
      f32x4 uf[4];
#pragma unroll
      for (int nt = 0; nt < 4; ++nt)
        uf[nt] = *(const f32x4*)&M2[tokX*NH + n0w + nt*16 + g*4];
      tokX = xrowX[tnext];

      f32x4 acc[4];
#pragma unroll
      for (int nt = 0; nt < 4; ++nt) acc[nt] = f32x4{0.f,0.f,0.f,0.f};
      f32x4 oacc = bfcf;

      COMPUTE16(0, p)

      if (t > 0) {
        float* po = out + ((size_t)(rowX + m)*NS + (t - 1))*NV + v0w + g*4;
        *(f32x4*)po = oacc;
      }

      // tanh + publish h_X(t): own half -> hlds[0][pn] + exch slot p
      h16* exo = exoX + p*8192;
#pragma unroll
      for (int nt = 0; nt < 4; ++nt) {
        const f32x4 a = acc[nt];
        half4v hv;
#pragma unroll
        for (int r = 0; r < 4; ++r) hv[r] = (h16)tanh_fast(a[r] + uf[nt][r]);
        const int kb = n0w + nt*16 + g*4;
        *(half4v*)&hlds[0][pn][m][kb ^ swz] = hv;
        union { half4v v; u64 u; } cv; cv.v = hv;
        __hip_atomic_store((u64*)&exo[m*256 + (w*64 + nt*16 + g*4)], cv.u,
                           __ATOMIC_RELAXED, __HIP_MEMORY_SCOPE_AGENT);
      }

      // consume Y-import(t) (issued end of previous macro; RTT hidden under phase X)
      if (t > 0) {
        u64* q0 = (u64*)&hlds[1][p][mm][(pk) ^ swzm];
        u64* q1 = (u64*)&hlds[1][p][mm][(pk + 8) ^ swzm];
        q0[0] = dY0; q0[1] = dY1; q1[0] = dY2; q1[1] = dY3;
      }

      int fX = __hip_atomic_load(fXpar, __ATOMIC_ACQUIRE, __HIP_MEMORY_SCOPE_AGENT);
      __syncthreads();   // BARRIER 1: exchX drained, hlds[1][p] import + hlds[0][pn] own visible
      if (tid == 0)
        __hip_atomic_store(fXown, t + 1, __ATOMIC_RELEASE, __HIP_MEMORY_SCOPE_AGENT);
      while (fX < t + 1) {
        __builtin_amdgcn_s_sleep(1);
        fX = __hip_atomic_load(fXpar, __ATOMIC_ACQUIRE, __HIP_MEMORY_SCOPE_AGENT);
      }
      { // issue X-import(t+1): partner h_X(t), consumed at end of phase Y
        const u64* sp = (const u64*)&exiX[p*8192 + mm*256 + m*16];
        dX0 = __hip_atomic_load(sp + 0, __ATOMIC_RELAXED, __HIP_MEMORY_SCOPE_AGENT);
        dX1 = __hip_atomic_load(sp + 1, __ATOMIC_RELAXED, __HIP_MEMORY_SCOPE_AGENT);
        dX2 = __hip_atomic_load(sp + 2, __ATOMIC_RELAXED, __HIP_MEMORY_SCOPE_AGENT);
        dX3 = __hip_atomic_load(sp + 3, __ATOMIC_RELAXED, __HIP_MEMORY_SCOPE_AGENT);
      }
    }

    // ================= PHASE Y (cluster rows rowY..rowY+15) =================
    {
      f32x4 uf[4];
#pragma unroll
      for (int nt = 0; nt < 4; ++nt)
        uf[nt] = *(const f32x4*)&M2[tokY*NH + n0w + nt*16 + g*4];
      tokY = xrowY[tnext];

      f32x4 acc[4];
#pragma unroll
      for (int nt = 0; nt < 4; ++nt) acc[nt] = f32x4{0.f,0.f,0.f,0.f};
      f32x4 oacc = bfcf;

      COMPUTE16(1, p)

      if (t > 0) {
        float* po = out + ((size_t)(rowY + m)*NS + (t - 1))*NV + v0w + g*4;
        *(f32x4*)po = oacc;
      }

      h16* exo = exoY + p*8192;
#pragma unroll
      for (int nt = 0; nt < 4; ++nt) {
        const f32x4 a = acc[nt];
        half4v hv;
#pragma unroll
        for (int r = 0; r < 4; ++r) hv[r] = (h16)tanh_fast(a[r] + uf[nt][r]);
        const int kb = n0w + nt*16 + g*4;
        *(half4v*)&hlds[1][pn][m][kb ^ swz] = hv;
        union { half4v v; u64 u; } cv; cv.v = hv;
        __hip_atomic_store((u64*)&exo[m*256 + (w*64 + nt*16 + g*4)], cv.u,
                           __ATOMIC_RELAXED, __HIP_MEMORY_SCOPE_AGENT);
      }

      // consume X-import(t+1) (issued end of phase X; RTT hidden under phase Y)
      {
        u64* q0 = (u64*)&hlds[0][pn][mm][(pk) ^ swzm];
        u64* q1 = (u64*)&hlds[0][pn][mm][(pk + 8) ^ swzm];
        q0[0] = dX0; q0[1] = dX1; q1[0] = dX2; q1[1] = dX3;
      }

      int fY = __hip_atomic_load(fYpar, __ATOMIC_ACQUIRE, __HIP_MEMORY_SCOPE_AGENT);
      __syncthreads();   // BARRIER 2
      if (tid == 0)
        __hip_atomic_store(fYown, t + 1, __ATOMIC_RELEASE, __HIP_MEMORY_SCOPE_AGENT);
      while (fY < t + 1) {
        __builtin_amdgcn_s_sleep(1);
        fY = __hip_atomic_load(fYpar, __ATOMIC_ACQUIRE, __HIP_MEMORY_SCOPE_AGENT);
      }
      { // issue Y-import(t+1): partner h_Y(t), consumed next macro's phase X
        const u64* sp = (const u64*)&exiY[p*8192 + mm*256 + m*16];
        dY0 = __hip_atomic_load(sp + 0, __ATOMIC_RELAXED, __HIP_MEMORY_SCOPE_AGENT);
        dY1 = __hip_atomic_load(sp + 1, __ATOMIC_RELAXED, __HIP_MEMORY_SCOPE_AGENT);
        dY2 = __hip_atomic_load(sp + 2, __ATOMIC_RELAXED, __HIP_MEMORY_SCOPE_AGENT);
        dY3 = __hip_atomic_load(sp + 3, __ATOMIC_RELAXED, __HIP_MEMORY_SCOPE_AGENT);
      }
    }
  }

  // ---- tail: out[S-1] = h_{S-1}@Wfc + bfc; h(2047) lives in buf 0 ----
  { // finish Y's partner-half import for h(2047)
    u64* q0 = (u64*)&hlds[1][0][mm][(pk) ^ swzm];
    u64* q1 = (u64*)&hlds[1][0][mm][(pk + 8) ^ swzm];
    q0[0] = dY0; q0[1] = dY1; q1[0] = dY2; q1[1] = dY3;
  }
  __syncthreads();
#define TAILOUT(CI, TROW)                                                      \
  {                                                                            \
    f32x4 oacc = bfcf;                                                         \
    half8 bfr[8];                                                              \
    _Pragma("unroll")                                                          \
    for (int i = 0; i < 8; ++i)                                                \
      bfr[i] = *(const half8*)&hlds[CI][0][m][((i*32) + g*8) ^ swz];           \
    _Pragma("unroll")                                                          \
    for (int i = 0; i < 8; ++i)                                                \
      oacc = __builtin_amdgcn_mfma_f32_16x16x32_f16(                           \
          __builtin_bit_cast(half8, wfcf[i]), bfr[i], oacc, 0, 0, 0);          \
    _Pragma("unroll")                                                          \
    for (int i = 0; i < 8; ++i)                                                \
      bfr[i] = *(const half8*)&hlds[CI][0][m][(((i+8)*32) + g*8) ^ swz];       \
    _Pragma("unroll")                                                          \
    for (int i = 0; i < 8; ++i)                                                \
      oacc = __builtin_amdgcn_mfma_f32_16x16x32_f16(                           \
          __builtin_bit_cast(half8, wfcf[8+i]), bfr[i], oacc, 0, 0, 0);        \
    float* po = out + ((size_t)(TROW + m)*NS + (NS - 1))*NV + v0w + g*4;       \
    *(f32x4*)po = oacc;                                                        \
  }
  TAILOUT(0, rowX)
  TAILOUT(1, rowY)
}

extern "C" void kernel_launch(void* const* d_in, const int* in_sizes, int n_in,
                              void* d_out, int out_size, void* d_ws, size_t ws_size,
                              hipStream_t stream) {
  (void)in_sizes; (void)n_in; (void)out_size; (void)ws_size;
  const int*   x   = (const int*)d_in[0];
  const float* emb = (const float*)d_in[1];
  const float* Wx  = (const float*)d_in[2];
  const float* bx  = (const float*)d_in[3];
  const float* Wh  = (const float*)d_in[4];
  const float* bh  = (const float*)d_in[5];
  const float* Wfc = (const float*)d_in[6];
  const float* bfc = (const float*)d_in[7];
  float* out = (float*)d_out;
  unsigned char* ws = (unsigned char*)d_ws;

  hipLaunchKernelGGL(vrnn_prep, dim3(209), dim3(256), 0, stream,
                     emb, Wx, bx, Wh, bh, Wfc, ws);
  hipLaunchKernelGGL(vrnn_scan, dim3(8), dim3(256), 0, stream,
                     x, bfc, out, ws);
}